// Round 1
// baseline (640.050 us; speedup 1.0000x reference)
//
#include <hip/hip_runtime.h>
#include <hip/hip_bf16.h>

#define N_NODES 20000
#define N_EDGES 320000
#define IN_DIM  1024
#define H_HEADS 8
#define C_CH    64
#define HC      512
#define LEAKY   0.2f
#define LN_EPS  1e-5f

// Extended weight matrix: cols 0..511 = W_src, 512..519 = w1 (att_src folded),
// 520..527 = w2 (att_dst folded), 528..575 = zero pad.
#define BCOLS 576

// ---------------------------------------------------------------------------
// Build Wext from W_src, W_dst, att_src, att_dst.
// grid = 1024 (one block per k-row), block = 128
__global__ void prep_wext(const float* __restrict__ Wsrc,
                          const float* __restrict__ Wdst,
                          const float* __restrict__ att_src,
                          const float* __restrict__ att_dst,
                          float* __restrict__ Wext) {
    int k = blockIdx.x;       // 0..1023
    int t = threadIdx.x;      // 0..127
    // copy W_src row (512 floats via float4)
    const float4* ws4 = (const float4*)(Wsrc + (size_t)k * HC);
    float4* we4 = (float4*)(Wext + (size_t)k * BCOLS);
    we4[t] = ws4[t];
    if (t < 16) {
        // t in [0,8): w1 (a_src weights); t in [8,16): w2 (a_dst weights)
        int h = t & 7;
        const float* W   = (t < 8) ? Wsrc : Wdst;
        const float* att = (t < 8) ? att_src : att_dst;
        float s = 0.f;
        #pragma unroll
        for (int c = 0; c < C_CH; ++c)
            s += W[(size_t)k * HC + h * C_CH + c] * att[h * C_CH + c];
        Wext[(size_t)k * BCOLS + 512 + t] = s;
    } else if (t < 64) {
        // zero pad cols 528..575
        Wext[(size_t)k * BCOLS + 512 + t] = 0.f;
    }
}

// ---------------------------------------------------------------------------
// Fused GEMM: [20000 x 1024] @ [1024 x 576] -> xs [N][512], a_src [N][8], a_dst [N][8]
// BM=128, BN=64, BK=16; 256 threads; each thread computes 8 rows x 4 cols.
#define BM 128
#define BN 64
#define BK 16

__global__ __launch_bounds__(256) void gemm_fused(
        const float* __restrict__ X,      // [N_NODES][IN_DIM]
        const float* __restrict__ Wext,   // [IN_DIM][BCOLS]
        float* __restrict__ xs,           // [N_NODES][HC]
        float* __restrict__ a_srcv,       // [N_NODES][8]
        float* __restrict__ a_dstv) {     // [N_NODES][8]
    __shared__ float As[BK][BM + 4];      // transposed A tile
    __shared__ float Bs[BK][BN + 4];
    int bm = blockIdx.x;
    int bn = blockIdx.y;
    int t  = threadIdx.x;
    int tx = t & 15, ty = t >> 4;         // tx: col group, ty: row group
    int row0 = bm * BM;
    int col0 = bn * BN;

    float acc[8][4] = {};

    int a_r = t >> 2;                     // 0..63 (row within pass)
    int a_k = (t & 3) * 4;                // 0,4,8,12
    int b_r = t >> 4;                     // 0..15 (k within tile)
    int b_c = (t & 15) * 4;               // 0..60

    for (int k0 = 0; k0 < IN_DIM; k0 += BK) {
        // stage A (128x16), transposed into As[k][m]
        #pragma unroll
        for (int p = 0; p < 2; ++p) {
            int m  = a_r + p * 64;
            int gm = row0 + m;
            float4 v = make_float4(0.f, 0.f, 0.f, 0.f);
            if (gm < N_NODES)
                v = *(const float4*)(X + (size_t)gm * IN_DIM + k0 + a_k);
            As[a_k + 0][m] = v.x;
            As[a_k + 1][m] = v.y;
            As[a_k + 2][m] = v.z;
            As[a_k + 3][m] = v.w;
        }
        // stage B (16x64)
        {
            float4 v = *(const float4*)(Wext + (size_t)(k0 + b_r) * BCOLS + col0 + b_c);
            *(float4*)(&Bs[b_r][b_c]) = v;
        }
        __syncthreads();
        #pragma unroll
        for (int kk = 0; kk < BK; ++kk) {
            float4 a0 = *(const float4*)(&As[kk][ty * 8]);
            float4 a1 = *(const float4*)(&As[kk][ty * 8 + 4]);
            float4 b  = *(const float4*)(&Bs[kk][tx * 4]);
            float av[8] = {a0.x, a0.y, a0.z, a0.w, a1.x, a1.y, a1.z, a1.w};
            float bv[4] = {b.x, b.y, b.z, b.w};
            #pragma unroll
            for (int i = 0; i < 8; ++i)
                #pragma unroll
                for (int j = 0; j < 4; ++j)
                    acc[i][j] = fmaf(av[i], bv[j], acc[i][j]);
        }
        __syncthreads();
    }

    // epilogue: route columns to xs / a_src / a_dst
    #pragma unroll
    for (int i = 0; i < 8; ++i) {
        int gm = row0 + ty * 8 + i;
        if (gm >= N_NODES) continue;
        int gc = col0 + tx * 4;
        if (gc + 3 < HC) {
            *(float4*)(xs + (size_t)gm * HC + gc) =
                make_float4(acc[i][0], acc[i][1], acc[i][2], acc[i][3]);
        } else {
            #pragma unroll
            for (int j = 0; j < 4; ++j) {
                int c = gc + j;
                if (c < HC)            xs[(size_t)gm * HC + c]       = acc[i][j];
                else if (c < 520)      a_srcv[gm * 8 + (c - 512)]    = acc[i][j];
                else if (c < 528)      a_dstv[gm * 8 + (c - 520)]    = acc[i][j];
            }
        }
    }
}

// ---------------------------------------------------------------------------
// degree histogram over dst
__global__ void deg_count(const int* __restrict__ ei, int* __restrict__ deg) {
    int e = blockIdx.x * blockDim.x + threadIdx.x;
    if (e < N_EDGES) atomicAdd(&deg[ei[N_EDGES + e]], 1);
}

// single-block exclusive scan over deg -> off[N+1], cursor copy
__global__ void scan_kernel(const int* __restrict__ deg,
                            int* __restrict__ off,
                            int* __restrict__ cursor) {
    __shared__ int s[1024];
    __shared__ int carry_s;
    int t = threadIdx.x;
    if (t == 0) carry_s = 0;
    __syncthreads();
    for (int base = 0; base < N_NODES; base += 1024) {
        int i = base + t;
        int v = (i < N_NODES) ? deg[i] : 0;
        s[t] = v;
        __syncthreads();
        for (int d = 1; d < 1024; d <<= 1) {
            int add = (t >= d) ? s[t - d] : 0;
            __syncthreads();
            s[t] += add;
            __syncthreads();
        }
        int incl  = s[t];
        int carry = carry_s;
        int excl  = carry + incl - v;
        if (i < N_NODES) { off[i] = excl; cursor[i] = excl; }
        __syncthreads();
        if (t == 1023) carry_s = carry + incl;
        __syncthreads();
    }
    if (t == 0) off[N_NODES] = carry_s;
}

// ---------------------------------------------------------------------------
// per-edge: scores (softmax max-shift skipped: shift-invariant), exp, denom
// accumulation, CSR scatter of (src, ex[8]).
__global__ void edge_scatter(const int* __restrict__ ei,
                             const float* __restrict__ a_srcv,
                             const float* __restrict__ a_dstv,
                             int* __restrict__ cursor,
                             float* __restrict__ denom,
                             int* __restrict__ csr_src,
                             float* __restrict__ csr_ex) {
    int e = blockIdx.x * blockDim.x + threadIdx.x;
    if (e >= N_EDGES) return;
    int s = ei[e];
    int d = ei[N_EDGES + e];
    int idx = atomicAdd(&cursor[d], 1);
    csr_src[idx] = s;
    #pragma unroll
    for (int h = 0; h < H_HEADS; ++h) {
        float sc = a_srcv[s * 8 + h] + a_dstv[d * 8 + h];
        sc = (sc >= 0.f) ? sc : LEAKY * sc;
        float ex = __expf(sc);
        atomicAdd(&denom[d * 8 + h], ex);
        csr_ex[(size_t)idx * 8 + h] = ex;
    }
}

// ---------------------------------------------------------------------------
// one block per destination node: weighted aggregation of incoming xs rows,
// then fused bias + LayerNorm + PReLU. 256 threads, 2 channels each.
__global__ __launch_bounds__(256) void aggregate_ln(
        const int* __restrict__ off,
        const int* __restrict__ csr_src,
        const float* __restrict__ csr_ex,
        const float* __restrict__ denom,
        const float* __restrict__ xs,
        const float* __restrict__ bias,
        const float* __restrict__ gamma,
        const float* __restrict__ beta,
        const float* __restrict__ prelu_a,
        float* __restrict__ out) {
    int n  = blockIdx.x;
    int t  = threadIdx.x;
    int ch = t * 2;
    int h  = ch >> 6;
    int start = off[n], end = off[n + 1];

    float2 acc = make_float2(0.f, 0.f);
    for (int i = start; i < end; ++i) {
        int s   = csr_src[i];
        float w = csr_ex[(size_t)i * 8 + h];
        float2 v = *(const float2*)(xs + (size_t)s * HC + ch);
        acc.x = fmaf(w, v.x, acc.x);
        acc.y = fmaf(w, v.y, acc.y);
    }
    float inv = 1.f / (denom[n * 8 + h] + 1e-16f);
    float vx = acc.x * inv + bias[ch];
    float vy = acc.y * inv + bias[ch + 1];

    // block LayerNorm over 512 channels
    float sum = vx + vy;
    float sq  = vx * vx + vy * vy;
    #pragma unroll
    for (int o = 32; o > 0; o >>= 1) {
        sum += __shfl_down(sum, o);
        sq  += __shfl_down(sq, o);
    }
    __shared__ float s_sum[4], s_sq[4];
    int wid = t >> 6;
    if ((t & 63) == 0) { s_sum[wid] = sum; s_sq[wid] = sq; }
    __syncthreads();
    float ts = s_sum[0] + s_sum[1] + s_sum[2] + s_sum[3];
    float tq = s_sq[0] + s_sq[1] + s_sq[2] + s_sq[3];
    float mu  = ts * (1.f / (float)HC);
    float var = tq * (1.f / (float)HC) - mu * mu;
    float rstd = rsqrtf(var + LN_EPS);

    float y0 = (vx - mu) * rstd * gamma[ch]     + beta[ch];
    float y1 = (vy - mu) * rstd * gamma[ch + 1] + beta[ch + 1];
    y0 = (y0 >= 0.f) ? y0 : prelu_a[ch] * y0;
    y1 = (y1 >= 0.f) ? y1 : prelu_a[ch + 1] * y1;
    *(float2*)(out + (size_t)n * HC + ch) = make_float2(y0, y1);
}

// ---------------------------------------------------------------------------
extern "C" void kernel_launch(void* const* d_in, const int* in_sizes, int n_in,
                              void* d_out, int out_size, void* d_ws, size_t ws_size,
                              hipStream_t stream) {
    const float* x        = (const float*)d_in[0];
    // d_in[1] edge_attr: unused (with_edge == 'N')
    const int*   ei       = (const int*)d_in[2];
    // d_in[3] batch: unused (LayerNorm over all rows is equivalent)
    const float* Wsrc     = (const float*)d_in[4];
    const float* Wdst     = (const float*)d_in[5];
    const float* att_src  = (const float*)d_in[6];
    const float* att_dst  = (const float*)d_in[7];
    const float* bias     = (const float*)d_in[8];
    const float* gamma    = (const float*)d_in[9];
    const float* beta     = (const float*)d_in[10];
    const float* prelu_a  = (const float*)d_in[11];
    float* out            = (float*)d_out;

    char*  ws = (char*)d_ws;
    size_t o  = 0;
    auto alloc = [&](size_t bytes) -> void* {
        void* p = ws + o;
        o += (bytes + 255) & ~(size_t)255;
        return p;
    };
    float* Wext    = (float*)alloc(sizeof(float) * IN_DIM * BCOLS);    // 2.36 MB
    float* xs      = (float*)alloc(sizeof(float) * N_NODES * HC);      // 40.96 MB
    float* a_srcv  = (float*)alloc(sizeof(float) * N_NODES * 8);       // 0.64 MB
    float* a_dstv  = (float*)alloc(sizeof(float) * N_NODES * 8);       // 0.64 MB
    float* denom   = (float*)alloc(sizeof(float) * N_NODES * 8);       // 0.64 MB
    int*   deg     = (int*)alloc(sizeof(int) * N_NODES);
    int*   off     = (int*)alloc(sizeof(int) * (N_NODES + 1));
    int*   cursor  = (int*)alloc(sizeof(int) * N_NODES);
    int*   csr_src = (int*)alloc(sizeof(int) * N_EDGES);               // 1.28 MB
    float* csr_ex  = (float*)alloc(sizeof(float) * (size_t)N_EDGES * 8); // 10.24 MB

    hipMemsetAsync(deg,   0, sizeof(int) * N_NODES, stream);
    hipMemsetAsync(denom, 0, sizeof(float) * N_NODES * 8, stream);

    prep_wext<<<IN_DIM, 128, 0, stream>>>(Wsrc, Wdst, att_src, att_dst, Wext);

    dim3 ggrid((N_NODES + BM - 1) / BM, BCOLS / BN);   // (157, 9)
    gemm_fused<<<ggrid, 256, 0, stream>>>(x, Wext, xs, a_srcv, a_dstv);

    deg_count<<<(N_EDGES + 255) / 256, 256, 0, stream>>>(ei, deg);
    scan_kernel<<<1, 1024, 0, stream>>>(deg, off, cursor);
    edge_scatter<<<(N_EDGES + 255) / 256, 256, 0, stream>>>(
        ei, a_srcv, a_dstv, cursor, denom, csr_src, csr_ex);
    aggregate_ln<<<N_NODES, 256, 0, stream>>>(
        off, csr_src, csr_ex, denom, xs, bias, gamma, beta, prelu_a, out);
}

// Round 2
// 307.630 us; speedup vs baseline: 2.0806x; 2.0806x over previous
//
#include <hip/hip_runtime.h>
#include <hip/hip_bf16.h>

#define N_NODES 20000
#define N_EDGES 320000
#define IN_DIM  1024
#define H_HEADS 8
#define C_CH    64
#define HC      512
#define LEAKY   0.2f
#define LN_EPS  1e-5f

// Extended (transposed) weight: rows 0..511 = W_src cols, 512..519 = att_src fold,
// 520..527 = att_dst fold, 528..575 zero pad.  wbT[col][k], bf16.
#define BCOLS 576

typedef short bf16x8 __attribute__((ext_vector_type(8)));
typedef float f32x4  __attribute__((ext_vector_type(4)));

__device__ __forceinline__ unsigned short f2bf(float f) {
    union { float f; unsigned int u; } c; c.f = f;
    unsigned int u = c.u;
    unsigned int r = (u + 0x7fffu + ((u >> 16) & 1u)) >> 16;   // RNE
    return (unsigned short)r;
}
__device__ __forceinline__ float bf2f(unsigned int h) {
    union { unsigned int u; float f; } c; c.u = h << 16; return c.f;
}

// ---------------------------------------------------------------------------
// Build wbT (bf16, [BCOLS][IN_DIM]) from W_src, W_dst, att_src, att_dst.
// grid = 1024 (one block per k), block = 128
__global__ void prep_w(const float* __restrict__ Wsrc,
                       const float* __restrict__ Wdst,
                       const float* __restrict__ att_src,
                       const float* __restrict__ att_dst,
                       short* __restrict__ wbT) {
    int k = blockIdx.x;
    int t = threadIdx.x;
    float4 v = *(const float4*)(Wsrc + (size_t)k * HC + t * 4);
    wbT[(size_t)(t * 4 + 0) * IN_DIM + k] = (short)f2bf(v.x);
    wbT[(size_t)(t * 4 + 1) * IN_DIM + k] = (short)f2bf(v.y);
    wbT[(size_t)(t * 4 + 2) * IN_DIM + k] = (short)f2bf(v.z);
    wbT[(size_t)(t * 4 + 3) * IN_DIM + k] = (short)f2bf(v.w);
    if (t < 16) {
        int h = t & 7;
        const float* W   = (t < 8) ? Wsrc : Wdst;
        const float* att = (t < 8) ? att_src : att_dst;
        float s = 0.f;
        #pragma unroll
        for (int c = 0; c < C_CH; ++c)
            s += W[(size_t)k * HC + h * C_CH + c] * att[h * C_CH + c];
        wbT[(size_t)(512 + t) * IN_DIM + k] = (short)f2bf(s);
    } else if (t < 64) {
        wbT[(size_t)(512 + t) * IN_DIM + k] = 0;   // pad cols 528..575
    }
}

// ---------------------------------------------------------------------------
// MFMA GEMM: X[20000x1024]fp32 @ wbT^T -> xs(bf16)[N][512], a_src/a_dst fp32 [N][8]
// Tile BM=64 x BN=192 x BK=64.  256 threads = 4 waves, wave w owns cols w*48..w*48+47.
// LDS layouts (16B slots): A[kc 0..7][m 0..63][8 bf16], B[kc 0..7][col 0..191][8 bf16]
#define BM 64
#define BN 192
#define BK 64

__global__ __launch_bounds__(256) void gemm_mfma(
        const float* __restrict__ X,
        const short* __restrict__ wbT,
        short* __restrict__ xsb,          // [N][512] bf16
        float* __restrict__ a_srcv,
        float* __restrict__ a_dstv) {
    __shared__ short As[8 * BM * 8];      // 8 KB
    __shared__ short Bs[8 * BN * 8];      // 24 KB

    int t    = threadIdx.x;
    int lane = t & 63;
    int w    = t >> 6;                    // wave 0..3
    int lr   = lane & 15;
    int lg   = lane >> 4;                 // 0..3
    int row0 = blockIdx.y * BM;
    int col0 = blockIdx.x * BN;
    int wn   = w * 48;

    f32x4 acc[4][3] = {};                 // mi (rows) x ni (cols)

    for (int k0 = 0; k0 < IN_DIM; k0 += BK) {
        // ---- stage A: 64 rows x 64 k fp32 -> bf16, layout [kq>>1][m][8]
        #pragma unroll
        for (int i = 0; i < 4; ++i) {
            int lid = t + 256 * i;
            int m   = lid & 63;
            int kq  = lid >> 6;           // 0..15 (4-float group)
            float4 v = make_float4(0.f, 0.f, 0.f, 0.f);
            int gm = row0 + m;
            if (gm < N_NODES)
                v = *(const float4*)(X + (size_t)gm * IN_DIM + k0 + kq * 4);
            unsigned int lo = (unsigned int)f2bf(v.x) | ((unsigned int)f2bf(v.y) << 16);
            unsigned int hi = (unsigned int)f2bf(v.z) | ((unsigned int)f2bf(v.w) << 16);
            int slot = (kq >> 1) * BM + m;
            *(uint2*)(&As[slot * 8 + (kq & 1) * 4]) = make_uint2(lo, hi);
        }
        // ---- stage B: 192 cols x 64 k bf16, layout [kc][col][8] (slot = s)
        #pragma unroll
        for (int i = 0; i < 6; ++i) {
            int s   = t + 256 * i;        // 0..1535
            int col = s % BN;
            int kc  = s / BN;             // 0..7
            *(int4*)(&Bs[s * 8]) =
                *(const int4*)(&wbT[(size_t)(col0 + col) * IN_DIM + k0 + kc * 8]);
        }
        __syncthreads();
        // ---- MFMA: 2 k-substeps of 32
        #pragma unroll
        for (int ks = 0; ks < 2; ++ks) {
            int kc = ks * 4 + lg;
            bf16x8 af[4], bfr[3];
            #pragma unroll
            for (int mi = 0; mi < 4; ++mi)
                af[mi] = *(const bf16x8*)(&As[(kc * BM + mi * 16 + lr) * 8]);
            #pragma unroll
            for (int ni = 0; ni < 3; ++ni)
                bfr[ni] = *(const bf16x8*)(&Bs[(kc * BN + wn + ni * 16 + lr) * 8]);
            #pragma unroll
            for (int mi = 0; mi < 4; ++mi)
                #pragma unroll
                for (int ni = 0; ni < 3; ++ni)
                    acc[mi][ni] = __builtin_amdgcn_mfma_f32_16x16x32_bf16(
                        af[mi], bfr[ni], acc[mi][ni], 0, 0, 0);
        }
        __syncthreads();
    }

    // ---- epilogue: C/D layout col=lane&15, row=(lane>>4)*4+reg
    #pragma unroll
    for (int mi = 0; mi < 4; ++mi) {
        #pragma unroll
        for (int r = 0; r < 4; ++r) {
            int row = row0 + mi * 16 + lg * 4 + r;
            if (row >= N_NODES) continue;
            #pragma unroll
            for (int ni = 0; ni < 3; ++ni) {
                int col = col0 + wn + ni * 16 + lr;
                float v = acc[mi][ni][r];
                if (col < 512)      xsb[(size_t)row * HC + col] = (short)f2bf(v);
                else if (col < 520) a_srcv[row * 8 + (col - 512)] = v;
                else if (col < 528) a_dstv[row * 8 + (col - 520)] = v;
            }
        }
    }
}

// ---------------------------------------------------------------------------
__global__ void deg_count(const int* __restrict__ ei, int* __restrict__ deg) {
    int e = blockIdx.x * blockDim.x + threadIdx.x;
    if (e < N_EDGES) atomicAdd(&deg[ei[N_EDGES + e]], 1);
}

// 1 block, 256 threads; each thread scans 80 contiguous elements.
__global__ void scan_kernel(const int* __restrict__ deg,
                            int* __restrict__ off,
                            int* __restrict__ cursor) {
    __shared__ int wtot[4];
    int t = threadIdx.x;
    int lane = t & 63, w = t >> 6;
    int base = t * 80;
    int s = 0;
    for (int i = 0; i < 80; ++i) {
        int idx = base + i;
        if (idx < N_NODES) s += deg[idx];
    }
    int v = s;
    #pragma unroll
    for (int o = 1; o < 64; o <<= 1) {
        int u = __shfl_up(v, o);
        if (lane >= o) v += u;
    }
    if (lane == 63) wtot[w] = v;
    __syncthreads();
    int add = 0;
    for (int j = 0; j < w; ++j) add += wtot[j];
    int run = add + v - s;                 // exclusive prefix of this segment
    for (int i = 0; i < 80; ++i) {
        int idx = base + i;
        if (idx < N_NODES) {
            off[idx] = run; cursor[idx] = run;
            run += deg[idx];
        }
    }
    if (t == 255) off[N_NODES] = run;
}

// ---------------------------------------------------------------------------
// per-edge: leaky-relu score, exp (softmax shift skipped: shift-invariant,
// scores O(+-5)), CSR scatter of (src, ex[8]).  denom now computed in aggregate.
__global__ void edge_scatter(const int* __restrict__ ei,
                             const float* __restrict__ a_srcv,
                             const float* __restrict__ a_dstv,
                             int* __restrict__ cursor,
                             int* __restrict__ csr_src,
                             float* __restrict__ csr_ex) {
    int e = blockIdx.x * blockDim.x + threadIdx.x;
    if (e >= N_EDGES) return;
    int s = ei[e];
    int d = ei[N_EDGES + e];
    int idx = atomicAdd(&cursor[d], 1);
    csr_src[idx] = s;
    float4 s0 = *(const float4*)(a_srcv + (size_t)s * 8);
    float4 s1 = *(const float4*)(a_srcv + (size_t)s * 8 + 4);
    float4 d0 = *(const float4*)(a_dstv + (size_t)d * 8);
    float4 d1 = *(const float4*)(a_dstv + (size_t)d * 8 + 4);
    float sc[8] = {s0.x + d0.x, s0.y + d0.y, s0.z + d0.z, s0.w + d0.w,
                   s1.x + d1.x, s1.y + d1.y, s1.z + d1.z, s1.w + d1.w};
    float ex[8];
    #pragma unroll
    for (int h = 0; h < 8; ++h) {
        float v = sc[h];
        v = (v >= 0.f) ? v : LEAKY * v;
        ex[h] = __expf(v);
    }
    *(float4*)(csr_ex + (size_t)idx * 8)     = make_float4(ex[0], ex[1], ex[2], ex[3]);
    *(float4*)(csr_ex + (size_t)idx * 8 + 4) = make_float4(ex[4], ex[5], ex[6], ex[7]);
}

// ---------------------------------------------------------------------------
// one block per destination node: weighted aggregation of incoming bf16 xs rows
// (+ local denom), then fused bias + LayerNorm + PReLU.
__global__ __launch_bounds__(256) void aggregate_ln(
        const int* __restrict__ off,
        const int* __restrict__ csr_src,
        const float* __restrict__ csr_ex,
        const short* __restrict__ xsb,
        const float* __restrict__ bias,
        const float* __restrict__ gamma,
        const float* __restrict__ beta,
        const float* __restrict__ prelu_a,
        float* __restrict__ out) {
    int n  = blockIdx.x;
    int t  = threadIdx.x;
    int ch = t * 2;
    int h  = ch >> 6;
    int start = off[n], end = off[n + 1];

    float ax = 0.f, ay = 0.f, wsum = 0.f;
    for (int i = start; i < end; ++i) {
        int s   = csr_src[i];
        float w = csr_ex[(size_t)i * 8 + h];
        unsigned int v = *(const unsigned int*)(xsb + (size_t)s * HC + ch);
        ax = fmaf(w, bf2f(v & 0xffffu), ax);
        ay = fmaf(w, bf2f(v >> 16), ay);
        wsum += w;
    }
    float inv = 1.f / (wsum + 1e-16f);
    float vx = ax * inv + bias[ch];
    float vy = ay * inv + bias[ch + 1];

    float sum = vx + vy;
    float sq  = vx * vx + vy * vy;
    #pragma unroll
    for (int o = 32; o > 0; o >>= 1) {
        sum += __shfl_down(sum, o);
        sq  += __shfl_down(sq, o);
    }
    __shared__ float s_sum[4], s_sq[4];
    int wid = t >> 6;
    if ((t & 63) == 0) { s_sum[wid] = sum; s_sq[wid] = sq; }
    __syncthreads();
    float ts = s_sum[0] + s_sum[1] + s_sum[2] + s_sum[3];
    float tq = s_sq[0] + s_sq[1] + s_sq[2] + s_sq[3];
    float mu   = ts * (1.f / (float)HC);
    float var  = tq * (1.f / (float)HC) - mu * mu;
    float rstd = rsqrtf(var + LN_EPS);

    float y0 = (vx - mu) * rstd * gamma[ch]     + beta[ch];
    float y1 = (vy - mu) * rstd * gamma[ch + 1] + beta[ch + 1];
    y0 = (y0 >= 0.f) ? y0 : prelu_a[ch] * y0;
    y1 = (y1 >= 0.f) ? y1 : prelu_a[ch + 1] * y1;
    *(float2*)(out + (size_t)n * HC + ch) = make_float2(y0, y1);
}

// ---------------------------------------------------------------------------
extern "C" void kernel_launch(void* const* d_in, const int* in_sizes, int n_in,
                              void* d_out, int out_size, void* d_ws, size_t ws_size,
                              hipStream_t stream) {
    const float* x        = (const float*)d_in[0];
    const int*   ei       = (const int*)d_in[2];
    const float* Wsrc     = (const float*)d_in[4];
    const float* Wdst     = (const float*)d_in[5];
    const float* att_src  = (const float*)d_in[6];
    const float* att_dst  = (const float*)d_in[7];
    const float* bias     = (const float*)d_in[8];
    const float* gamma    = (const float*)d_in[9];
    const float* beta     = (const float*)d_in[10];
    const float* prelu_a  = (const float*)d_in[11];
    float* out            = (float*)d_out;

    char*  ws = (char*)d_ws;
    size_t o  = 0;
    auto alloc = [&](size_t bytes) -> void* {
        void* p = ws + o;
        o += (bytes + 255) & ~(size_t)255;
        return p;
    };
    short* wbT     = (short*)alloc(sizeof(short) * BCOLS * IN_DIM);        // 1.18 MB
    short* xsb     = (short*)alloc(sizeof(short) * (size_t)N_NODES * HC);  // 20.5 MB
    float* a_srcv  = (float*)alloc(sizeof(float) * N_NODES * 8);
    float* a_dstv  = (float*)alloc(sizeof(float) * N_NODES * 8);
    int*   deg     = (int*)alloc(sizeof(int) * N_NODES);
    int*   off     = (int*)alloc(sizeof(int) * (N_NODES + 1));
    int*   cursor  = (int*)alloc(sizeof(int) * N_NODES);
    int*   csr_src = (int*)alloc(sizeof(int) * N_EDGES);                   // 1.28 MB
    float* csr_ex  = (float*)alloc(sizeof(float) * (size_t)N_EDGES * 8);   // 10.24 MB

    hipMemsetAsync(deg, 0, sizeof(int) * N_NODES, stream);

    prep_w<<<IN_DIM, 128, 0, stream>>>(Wsrc, Wdst, att_src, att_dst, wbT);

    dim3 ggrid(BCOLS / BN, (N_NODES + BM - 1) / BM);   // (3, 313) — col tiles fastest
    gemm_mfma<<<ggrid, 256, 0, stream>>>(x, wbT, xsb, a_srcv, a_dstv);

    deg_count<<<(N_EDGES + 255) / 256, 256, 0, stream>>>(ei, deg);
    scan_kernel<<<1, 256, 0, stream>>>(deg, off, cursor);
    edge_scatter<<<(N_EDGES + 255) / 256, 256, 0, stream>>>(
        ei, a_srcv, a_dstv, cursor, csr_src, csr_ex);
    aggregate_ln<<<N_NODES, 256, 0, stream>>>(
        off, csr_src, csr_ex, xsb, bias, gamma, beta, prelu_a, out);
}

// Round 3
// 257.225 us; speedup vs baseline: 2.4883x; 1.1960x over previous
//
#include <hip/hip_runtime.h>
#include <hip/hip_bf16.h>

#define N_NODES 20000
#define N_EDGES 320000
#define IN_DIM  1024
#define H_HEADS 8
#define C_CH    64
#define HC      512
#define LEAKY   0.2f
#define LN_EPS  1e-5f

// Extended (transposed) weight: rows 0..511 = W_src cols, 512..519 = att_src fold,
// 520..527 = att_dst fold, 528..575 zero pad.  wbT[col][k], bf16.
#define BCOLS 576

typedef short bf16x8 __attribute__((ext_vector_type(8)));
typedef float f32x4  __attribute__((ext_vector_type(4)));

__device__ __forceinline__ unsigned short f2bf(float f) {
    union { float f; unsigned int u; } c; c.f = f;
    unsigned int u = c.u;
    unsigned int r = (u + 0x7fffu + ((u >> 16) & 1u)) >> 16;   // RNE
    return (unsigned short)r;
}
__device__ __forceinline__ float bf2f(unsigned int h) {
    union { unsigned int u; float f; } c; c.u = h << 16; return c.f;
}
__device__ __forceinline__ void gload_lds16(const void* g, void* l) {
    __builtin_amdgcn_global_load_lds(
        (const __attribute__((address_space(1))) unsigned int*)g,
        (__attribute__((address_space(3))) unsigned int*)l, 16, 0, 0);
}

// ---------------------------------------------------------------------------
// x fp32 [N][1024] -> xb bf16 (stored in d_out buffer, dead until final kernel)
__global__ __launch_bounds__(256) void convert_x(const float* __restrict__ x,
                                                 short* __restrict__ xb) {
    const int total = N_NODES * IN_DIM / 8;   // 2,560,000 chunks of 8
    int stride = gridDim.x * blockDim.x;
    for (int i = blockIdx.x * blockDim.x + threadIdx.x; i < total; i += stride) {
        float4 a = ((const float4*)x)[(size_t)i * 2];
        float4 b = ((const float4*)x)[(size_t)i * 2 + 1];
        uint4 r;
        r.x = (unsigned int)f2bf(a.x) | ((unsigned int)f2bf(a.y) << 16);
        r.y = (unsigned int)f2bf(a.z) | ((unsigned int)f2bf(a.w) << 16);
        r.z = (unsigned int)f2bf(b.x) | ((unsigned int)f2bf(b.y) << 16);
        r.w = (unsigned int)f2bf(b.z) | ((unsigned int)f2bf(b.w) << 16);
        *(uint4*)(&xb[(size_t)i * 8]) = r;
    }
}

// ---------------------------------------------------------------------------
// Build wbT (bf16, [BCOLS][IN_DIM]).  grid = 1024 (one block per k), block = 128
__global__ void prep_w(const float* __restrict__ Wsrc,
                       const float* __restrict__ Wdst,
                       const float* __restrict__ att_src,
                       const float* __restrict__ att_dst,
                       short* __restrict__ wbT) {
    int k = blockIdx.x;
    int t = threadIdx.x;
    float4 v = *(const float4*)(Wsrc + (size_t)k * HC + t * 4);
    wbT[(size_t)(t * 4 + 0) * IN_DIM + k] = (short)f2bf(v.x);
    wbT[(size_t)(t * 4 + 1) * IN_DIM + k] = (short)f2bf(v.y);
    wbT[(size_t)(t * 4 + 2) * IN_DIM + k] = (short)f2bf(v.z);
    wbT[(size_t)(t * 4 + 3) * IN_DIM + k] = (short)f2bf(v.w);
    if (t < 16) {
        int h = t & 7;
        const float* W   = (t < 8) ? Wsrc : Wdst;
        const float* att = (t < 8) ? att_src : att_dst;
        float s = 0.f;
        #pragma unroll
        for (int c = 0; c < C_CH; ++c)
            s += W[(size_t)k * HC + h * C_CH + c] * att[h * C_CH + c];
        wbT[(size_t)(512 + t) * IN_DIM + k] = (short)f2bf(s);
    } else if (t < 64) {
        wbT[(size_t)(512 + t) * IN_DIM + k] = 0;   // pad cols 528..575
    }
}

// ---------------------------------------------------------------------------
// MFMA GEMM: xb[20000x1024]bf16 @ wbT^T -> xsb bf16 [N][512], a_src/a_dst fp32 [N][8]
// BM=128 x BN=96 x BK=64.  256 threads = 4 waves in 2x2; all staging via
// global_load_lds (16B).  LDS 16B slots: A[kc 0..7][m 0..127], B[kc 0..7][col 0..95]
#define BM 128
#define BN 96
#define BK 64
#define NCOLT (BCOLS / BN)   // 6
#define NROWT ((N_NODES + BM - 1) / BM)   // 157
#define NWG (NCOLT * NROWT)  // 942

__global__ __launch_bounds__(256) void gemm_mfma(
        const short* __restrict__ xb,
        const short* __restrict__ wbT,
        short* __restrict__ xsb,
        float* __restrict__ a_srcv,
        float* __restrict__ a_dstv) {
    __shared__ short As[8 * BM * 8];      // 16 KB
    __shared__ short Bs[8 * BN * 8];      // 12 KB

    // bijective XCD swizzle (m204): contiguous grid chunk per XCD
    int orig = blockIdx.x;
    const int q = NWG >> 3, r = NWG & 7;
    int xcd  = orig & 7;
    int wgid = (xcd < r ? xcd * (q + 1) : r * (q + 1) + (xcd - r) * q) + (orig >> 3);
    int col0 = (wgid % NCOLT) * BN;       // col tiles fastest -> row-band L2 reuse
    int row0 = (wgid / NCOLT) * BM;

    int t    = threadIdx.x;
    int lane = t & 63;
    int w    = t >> 6;
    int lr   = lane & 15;
    int lg   = lane >> 4;
    int wr   = (w >> 1) * 64;             // wave row offset
    int wc   = (w & 1) * 48;              // wave col offset

    // hoisted staging coordinates
    int a_m[4], a_kc[4];
    #pragma unroll
    for (int i = 0; i < 4; ++i) {
        int slot = t + 256 * i;
        a_m[i]  = slot & 127;
        a_kc[i] = slot >> 7;
    }
    int b_col[3], b_kc[3];
    #pragma unroll
    for (int i = 0; i < 3; ++i) {
        int slot = t + 256 * i;
        b_col[i] = slot % BN;
        b_kc[i]  = slot / BN;
    }
    const short* a_src_base[4];
    #pragma unroll
    for (int i = 0; i < 4; ++i) {
        int gm = row0 + a_m[i];
        if (gm >= N_NODES) gm = N_NODES - 1;      // clamp (dead rows, keeps in-bounds)
        a_src_base[i] = xb + (size_t)gm * IN_DIM + a_kc[i] * 8;
    }
    const short* b_src_base[3];
    #pragma unroll
    for (int i = 0; i < 3; ++i)
        b_src_base[i] = wbT + (size_t)(col0 + b_col[i]) * IN_DIM + b_kc[i] * 8;

    f32x4 acc[4][3] = {};

    for (int k0 = 0; k0 < IN_DIM; k0 += BK) {
        #pragma unroll
        for (int i = 0; i < 4; ++i)
            gload_lds16(a_src_base[i] + k0, &As[(t + 256 * i) * 8]);
        #pragma unroll
        for (int i = 0; i < 3; ++i)
            gload_lds16(b_src_base[i] + k0, &Bs[(t + 256 * i) * 8]);
        __syncthreads();                  // drains vmcnt before compute

        #pragma unroll
        for (int ks = 0; ks < 2; ++ks) {
            int kc = ks * 4 + lg;
            bf16x8 af[4], bfr[3];
            #pragma unroll
            for (int mi = 0; mi < 4; ++mi)
                af[mi] = *(const bf16x8*)(&As[(kc * BM + wr + mi * 16 + lr) * 8]);
            #pragma unroll
            for (int ni = 0; ni < 3; ++ni)
                bfr[ni] = *(const bf16x8*)(&Bs[(kc * BN + wc + ni * 16 + lr) * 8]);
            #pragma unroll
            for (int mi = 0; mi < 4; ++mi)
                #pragma unroll
                for (int ni = 0; ni < 3; ++ni)
                    acc[mi][ni] = __builtin_amdgcn_mfma_f32_16x16x32_bf16(
                        af[mi], bfr[ni], acc[mi][ni], 0, 0, 0);
        }
        __syncthreads();
    }

    // epilogue: C/D layout col=lane&15, row=(lane>>4)*4+reg
    #pragma unroll
    for (int mi = 0; mi < 4; ++mi) {
        #pragma unroll
        for (int rr = 0; rr < 4; ++rr) {
            int row = row0 + wr + mi * 16 + lg * 4 + rr;
            if (row >= N_NODES) continue;
            #pragma unroll
            for (int ni = 0; ni < 3; ++ni) {
                int col = col0 + wc + ni * 16 + lr;
                float v = acc[mi][ni][rr];
                if (col < 512)      xsb[(size_t)row * HC + col] = (short)f2bf(v);
                else if (col < 520) a_srcv[(size_t)row * 8 + (col - 512)] = v;
                else if (col < 528) a_dstv[(size_t)row * 8 + (col - 520)] = v;
            }
        }
    }
}

// ---------------------------------------------------------------------------
__global__ void deg_count(const int* __restrict__ ei, int* __restrict__ deg) {
    int e = blockIdx.x * blockDim.x + threadIdx.x;
    if (e < N_EDGES) atomicAdd(&deg[ei[N_EDGES + e]], 1);
}

// 1 block, 256 threads; each thread scans 80 contiguous elements.
__global__ void scan_kernel(const int* __restrict__ deg,
                            int* __restrict__ off,
                            int* __restrict__ cursor) {
    __shared__ int wtot[4];
    int t = threadIdx.x;
    int lane = t & 63, w = t >> 6;
    int base = t * 80;
    int s = 0;
    for (int i = 0; i < 80; ++i) {
        int idx = base + i;
        if (idx < N_NODES) s += deg[idx];
    }
    int v = s;
    #pragma unroll
    for (int o = 1; o < 64; o <<= 1) {
        int u = __shfl_up(v, o);
        if (lane >= o) v += u;
    }
    if (lane == 63) wtot[w] = v;
    __syncthreads();
    int add = 0;
    for (int j = 0; j < w; ++j) add += wtot[j];
    int run = add + v - s;
    for (int i = 0; i < 80; ++i) {
        int idx = base + i;
        if (idx < N_NODES) {
            off[idx] = run; cursor[idx] = run;
            run += deg[idx];
        }
    }
    if (t == 255) off[N_NODES] = run;
}

// ---------------------------------------------------------------------------
// per-edge: leaky-relu score, exp (softmax shift skipped: shift-invariant,
// scores O(+-5)), CSR scatter of (src, ex[8]).
__global__ void edge_scatter(const int* __restrict__ ei,
                             const float* __restrict__ a_srcv,
                             const float* __restrict__ a_dstv,
                             int* __restrict__ cursor,
                             int* __restrict__ csr_src,
                             float* __restrict__ csr_ex) {
    int e = blockIdx.x * blockDim.x + threadIdx.x;
    if (e >= N_EDGES) return;
    int s = ei[e];
    int d = ei[N_EDGES + e];
    int idx = atomicAdd(&cursor[d], 1);
    csr_src[idx] = s;
    float4 s0 = *(const float4*)(a_srcv + (size_t)s * 8);
    float4 s1 = *(const float4*)(a_srcv + (size_t)s * 8 + 4);
    float4 d0 = *(const float4*)(a_dstv + (size_t)d * 8);
    float4 d1 = *(const float4*)(a_dstv + (size_t)d * 8 + 4);
    float sc[8] = {s0.x + d0.x, s0.y + d0.y, s0.z + d0.z, s0.w + d0.w,
                   s1.x + d1.x, s1.y + d1.y, s1.z + d1.z, s1.w + d1.w};
    float ex[8];
    #pragma unroll
    for (int h = 0; h < 8; ++h) {
        float v = sc[h];
        v = (v >= 0.f) ? v : LEAKY * v;
        ex[h] = __expf(v);
    }
    *(float4*)(csr_ex + (size_t)idx * 8)     = make_float4(ex[0], ex[1], ex[2], ex[3]);
    *(float4*)(csr_ex + (size_t)idx * 8 + 4) = make_float4(ex[4], ex[5], ex[6], ex[7]);
}

// ---------------------------------------------------------------------------
// one block per destination node: weighted aggregation of incoming bf16 xs rows
// (+ local denom), then fused bias + LayerNorm + PReLU.
__global__ __launch_bounds__(256) void aggregate_ln(
        const int* __restrict__ off,
        const int* __restrict__ csr_src,
        const float* __restrict__ csr_ex,
        const short* __restrict__ xsb,
        const float* __restrict__ bias,
        const float* __restrict__ gamma,
        const float* __restrict__ beta,
        const float* __restrict__ prelu_a,
        float* __restrict__ out) {
    int n  = blockIdx.x;
    int t  = threadIdx.x;
    int ch = t * 2;
    int h  = ch >> 6;
    int start = off[n], end = off[n + 1];

    float ax = 0.f, ay = 0.f, wsum = 0.f;
    int i = start;
    for (; i + 1 < end; i += 2) {
        int s0   = csr_src[i];
        int s1   = csr_src[i + 1];
        float w0 = csr_ex[(size_t)i * 8 + h];
        float w1 = csr_ex[(size_t)(i + 1) * 8 + h];
        unsigned int v0 = *(const unsigned int*)(xsb + (size_t)s0 * HC + ch);
        unsigned int v1 = *(const unsigned int*)(xsb + (size_t)s1 * HC + ch);
        ax = fmaf(w0, bf2f(v0 & 0xffffu), ax);
        ay = fmaf(w0, bf2f(v0 >> 16), ay);
        ax = fmaf(w1, bf2f(v1 & 0xffffu), ax);
        ay = fmaf(w1, bf2f(v1 >> 16), ay);
        wsum += w0 + w1;
    }
    if (i < end) {
        int s0   = csr_src[i];
        float w0 = csr_ex[(size_t)i * 8 + h];
        unsigned int v0 = *(const unsigned int*)(xsb + (size_t)s0 * HC + ch);
        ax = fmaf(w0, bf2f(v0 & 0xffffu), ax);
        ay = fmaf(w0, bf2f(v0 >> 16), ay);
        wsum += w0;
    }
    float inv = 1.f / (wsum + 1e-16f);
    float vx = ax * inv + bias[ch];
    float vy = ay * inv + bias[ch + 1];

    float sum = vx + vy;
    float sq  = vx * vx + vy * vy;
    #pragma unroll
    for (int o = 32; o > 0; o >>= 1) {
        sum += __shfl_down(sum, o);
        sq  += __shfl_down(sq, o);
    }
    __shared__ float s_sum[4], s_sq[4];
    int wid = t >> 6;
    if ((t & 63) == 0) { s_sum[wid] = sum; s_sq[wid] = sq; }
    __syncthreads();
    float ts = s_sum[0] + s_sum[1] + s_sum[2] + s_sum[3];
    float tq = s_sq[0] + s_sq[1] + s_sq[2] + s_sq[3];
    float mu   = ts * (1.f / (float)HC);
    float var  = tq * (1.f / (float)HC) - mu * mu;
    float rstd = rsqrtf(var + LN_EPS);

    float y0 = (vx - mu) * rstd * gamma[ch]     + beta[ch];
    float y1 = (vy - mu) * rstd * gamma[ch + 1] + beta[ch + 1];
    y0 = (y0 >= 0.f) ? y0 : prelu_a[ch] * y0;
    y1 = (y1 >= 0.f) ? y1 : prelu_a[ch + 1] * y1;
    *(float2*)(out + (size_t)n * HC + ch) = make_float2(y0, y1);
}

// ---------------------------------------------------------------------------
extern "C" void kernel_launch(void* const* d_in, const int* in_sizes, int n_in,
                              void* d_out, int out_size, void* d_ws, size_t ws_size,
                              hipStream_t stream) {
    const float* x        = (const float*)d_in[0];
    const int*   ei       = (const int*)d_in[2];
    const float* Wsrc     = (const float*)d_in[4];
    const float* Wdst     = (const float*)d_in[5];
    const float* att_src  = (const float*)d_in[6];
    const float* att_dst  = (const float*)d_in[7];
    const float* bias     = (const float*)d_in[8];
    const float* gamma    = (const float*)d_in[9];
    const float* beta     = (const float*)d_in[10];
    const float* prelu_a  = (const float*)d_in[11];
    float* out            = (float*)d_out;

    char*  ws = (char*)d_ws;
    size_t o  = 0;
    auto alloc = [&](size_t bytes) -> void* {
        void* p = ws + o;
        o += (bytes + 255) & ~(size_t)255;
        return p;
    };
    short* wbT     = (short*)alloc(sizeof(short) * BCOLS * IN_DIM);        // 1.18 MB
    short* xsb     = (short*)alloc(sizeof(short) * (size_t)N_NODES * HC);  // 20.5 MB
    float* a_srcv  = (float*)alloc(sizeof(float) * N_NODES * 8);
    float* a_dstv  = (float*)alloc(sizeof(float) * N_NODES * 8);
    int*   deg     = (int*)alloc(sizeof(int) * N_NODES);
    int*   off     = (int*)alloc(sizeof(int) * (N_NODES + 1));
    int*   cursor  = (int*)alloc(sizeof(int) * N_NODES);
    int*   csr_src = (int*)alloc(sizeof(int) * N_EDGES);                   // 1.28 MB
    float* csr_ex  = (float*)alloc(sizeof(float) * (size_t)N_EDGES * 8);   // 10.24 MB

    // xb (bf16 x) lives in d_out: exactly N*1024*2B = N*512*4B; d_out is dead
    // until aggregate_ln fully overwrites it.
    short* xb = (short*)d_out;

    hipMemsetAsync(deg, 0, sizeof(int) * N_NODES, stream);

    convert_x<<<2048, 256, 0, stream>>>(x, xb);
    prep_w<<<IN_DIM, 128, 0, stream>>>(Wsrc, Wdst, att_src, att_dst, wbT);

    gemm_mfma<<<NWG, 256, 0, stream>>>(xb, wbT, xsb, a_srcv, a_dstv);

    deg_count<<<(N_EDGES + 255) / 256, 256, 0, stream>>>(ei, deg);
    scan_kernel<<<1, 256, 0, stream>>>(deg, off, cursor);
    edge_scatter<<<(N_EDGES + 255) / 256, 256, 0, stream>>>(
        ei, a_srcv, a_dstv, cursor, csr_src, csr_ex);
    aggregate_ln<<<N_NODES, 256, 0, stream>>>(
        off, csr_src, csr_ex, xsb, bias, gamma, beta, prelu_a, out);
}

// Round 4
// 255.637 us; speedup vs baseline: 2.5038x; 1.0062x over previous
//
#include <hip/hip_runtime.h>
#include <hip/hip_bf16.h>

#define N_NODES 20000
#define N_EDGES 320000
#define IN_DIM  1024
#define H_HEADS 8
#define C_CH    64
#define HC      512
#define LEAKY   0.2f
#define LN_EPS  1e-5f

// Extended (transposed) weight: rows 0..511 = W_src cols, 512..519 = att_src fold,
// 520..527 = att_dst fold, 528..575 zero pad.  wbT[col][k], bf16.
#define BCOLS 576

typedef short bf16x8 __attribute__((ext_vector_type(8)));
typedef float f32x4  __attribute__((ext_vector_type(4)));

__device__ __forceinline__ unsigned short f2bf(float f) {
    union { float f; unsigned int u; } c; c.f = f;
    unsigned int u = c.u;
    unsigned int r = (u + 0x7fffu + ((u >> 16) & 1u)) >> 16;   // RNE
    return (unsigned short)r;
}
__device__ __forceinline__ float bf2f(unsigned int h) {
    union { unsigned int u; float f; } c; c.u = h << 16; return c.f;
}
__device__ __forceinline__ void gload_lds16(const void* g, void* l) {
    __builtin_amdgcn_global_load_lds(
        (const __attribute__((address_space(1))) unsigned int*)g,
        (__attribute__((address_space(3))) unsigned int*)l, 16, 0, 0);
}

// ---------------------------------------------------------------------------
// x fp32 [N][1024] -> xb bf16 (stored in d_out buffer, dead until final kernel)
__global__ __launch_bounds__(256) void convert_x(const float* __restrict__ x,
                                                 short* __restrict__ xb) {
    const int total = N_NODES * IN_DIM / 8;   // 2,560,000 chunks of 8
    int stride = gridDim.x * blockDim.x;
    for (int i = blockIdx.x * blockDim.x + threadIdx.x; i < total; i += stride) {
        float4 a = ((const float4*)x)[(size_t)i * 2];
        float4 b = ((const float4*)x)[(size_t)i * 2 + 1];
        uint4 r;
        r.x = (unsigned int)f2bf(a.x) | ((unsigned int)f2bf(a.y) << 16);
        r.y = (unsigned int)f2bf(a.z) | ((unsigned int)f2bf(a.w) << 16);
        r.z = (unsigned int)f2bf(b.x) | ((unsigned int)f2bf(b.y) << 16);
        r.w = (unsigned int)f2bf(b.z) | ((unsigned int)f2bf(b.w) << 16);
        *(uint4*)(&xb[(size_t)i * 8]) = r;
    }
}

// ---------------------------------------------------------------------------
// Build wbT (bf16, [BCOLS][IN_DIM]).  grid = 1024 (one block per k), block = 128
__global__ void prep_w(const float* __restrict__ Wsrc,
                       const float* __restrict__ Wdst,
                       const float* __restrict__ att_src,
                       const float* __restrict__ att_dst,
                       short* __restrict__ wbT) {
    int k = blockIdx.x;
    int t = threadIdx.x;
    float4 v = *(const float4*)(Wsrc + (size_t)k * HC + t * 4);
    wbT[(size_t)(t * 4 + 0) * IN_DIM + k] = (short)f2bf(v.x);
    wbT[(size_t)(t * 4 + 1) * IN_DIM + k] = (short)f2bf(v.y);
    wbT[(size_t)(t * 4 + 2) * IN_DIM + k] = (short)f2bf(v.z);
    wbT[(size_t)(t * 4 + 3) * IN_DIM + k] = (short)f2bf(v.w);
    if (t < 16) {
        int h = t & 7;
        const float* W   = (t < 8) ? Wsrc : Wdst;
        const float* att = (t < 8) ? att_src : att_dst;
        float s = 0.f;
        #pragma unroll
        for (int c = 0; c < C_CH; ++c)
            s += W[(size_t)k * HC + h * C_CH + c] * att[h * C_CH + c];
        wbT[(size_t)(512 + t) * IN_DIM + k] = (short)f2bf(s);
    } else if (t < 64) {
        wbT[(size_t)(512 + t) * IN_DIM + k] = 0;   // pad cols 528..575
    }
}

// ---------------------------------------------------------------------------
// MFMA GEMM: xb bf16 @ wbT^T -> xsb bf16 [N][512], a_src/a_dst fp32 [N][8]
// BM=128 x BN=96 x BK=64.  4 waves (2x2).  Double-buffered global_load_lds
// pipeline: stage(next) || compute(cur), one vmcnt(0)+barrier per K-step
// AFTER the MFMA cluster (T3 minimum 2-phase recipe).
#define BM 128
#define BN 96
#define BK 64
#define NCOLT (BCOLS / BN)                  // 6
#define NROWT ((N_NODES + BM - 1) / BM)     // 157
#define NWG (NCOLT * NROWT)                 // 942
#define KSTEPS (IN_DIM / BK)                // 16

__global__ __launch_bounds__(256) void gemm_mfma(
        const short* __restrict__ xb,
        const short* __restrict__ wbT,
        short* __restrict__ xsb,
        float* __restrict__ a_srcv,
        float* __restrict__ a_dstv) {
    __shared__ short As[2][8 * BM * 8];     // 2 x 16 KB
    __shared__ short Bs[2][8 * BN * 8];     // 2 x 12 KB

    // bijective XCD swizzle (m204): contiguous grid chunk per XCD
    int orig = blockIdx.x;
    const int q = NWG >> 3, r = NWG & 7;
    int xcd  = orig & 7;
    int wgid = (xcd < r ? xcd * (q + 1) : r * (q + 1) + (xcd - r) * q) + (orig >> 3);
    int col0 = (wgid % NCOLT) * BN;         // col tiles fastest -> row-band L2 reuse
    int row0 = (wgid / NCOLT) * BM;

    int t    = threadIdx.x;
    int lane = t & 63;
    int w    = t >> 6;
    int lr   = lane & 15;
    int lg   = lane >> 4;
    int wr   = (w >> 1) * 64;               // wave row offset
    int wc   = (w & 1) * 48;                // wave col offset

    // hoisted staging source pointers (7 x 16B DMA per thread per K-step)
    const short* a_src_base[4];
    #pragma unroll
    for (int i = 0; i < 4; ++i) {
        int slot = t + 256 * i;
        int gm = row0 + (slot & 127);
        if (gm >= N_NODES) gm = N_NODES - 1;   // clamp (dead rows, in-bounds)
        a_src_base[i] = xb + (size_t)gm * IN_DIM + (slot >> 7) * 8;
    }
    const short* b_src_base[3];
    #pragma unroll
    for (int i = 0; i < 3; ++i) {
        int slot = t + 256 * i;
        b_src_base[i] = wbT + (size_t)(col0 + slot % BN) * IN_DIM + (slot / BN) * 8;
    }

    f32x4 acc[4][3] = {};

#define STAGE(buf, k0)                                                      \
    do {                                                                    \
        _Pragma("unroll")                                                   \
        for (int i_ = 0; i_ < 4; ++i_)                                      \
            gload_lds16(a_src_base[i_] + (k0), &As[buf][(t + 256 * i_) * 8]); \
        _Pragma("unroll")                                                   \
        for (int i_ = 0; i_ < 3; ++i_)                                      \
            gload_lds16(b_src_base[i_] + (k0), &Bs[buf][(t + 256 * i_) * 8]); \
    } while (0)

    // prologue: stage tile 0, drain, barrier
    STAGE(0, 0);
    asm volatile("s_waitcnt vmcnt(0)" ::: "memory");
    __builtin_amdgcn_s_barrier();

    int cur = 0;
    for (int step = 0; step < KSTEPS; ++step) {
        if (step + 1 < KSTEPS) STAGE(cur ^ 1, (step + 1) * BK);   // prefetch in flight

        // compute current tile: ds_read + MFMA (compiler inserts lgkmcnt)
        __builtin_amdgcn_s_setprio(1);
        #pragma unroll
        for (int ks = 0; ks < 2; ++ks) {
            int kc = ks * 4 + lg;
            bf16x8 af[4], bfr[3];
            #pragma unroll
            for (int mi = 0; mi < 4; ++mi)
                af[mi] = *(const bf16x8*)(&As[cur][(kc * BM + wr + mi * 16 + lr) * 8]);
            #pragma unroll
            for (int ni = 0; ni < 3; ++ni)
                bfr[ni] = *(const bf16x8*)(&Bs[cur][(kc * BN + wc + ni * 16 + lr) * 8]);
            #pragma unroll
            for (int mi = 0; mi < 4; ++mi)
                #pragma unroll
                for (int ni = 0; ni < 3; ++ni)
                    acc[mi][ni] = __builtin_amdgcn_mfma_f32_16x16x32_bf16(
                        af[mi], bfr[ni], acc[mi][ni], 0, 0, 0);
        }
        __builtin_amdgcn_s_setprio(0);

        // drain prefetch (latency already hidden under MFMA), sync buffers
        asm volatile("s_waitcnt vmcnt(0)" ::: "memory");
        __builtin_amdgcn_s_barrier();
        cur ^= 1;
    }
#undef STAGE

    // epilogue: C/D layout col=lane&15, row=(lane>>4)*4+reg
    #pragma unroll
    for (int mi = 0; mi < 4; ++mi) {
        #pragma unroll
        for (int rr = 0; rr < 4; ++rr) {
            int row = row0 + wr + mi * 16 + lg * 4 + rr;
            if (row >= N_NODES) continue;
            #pragma unroll
            for (int ni = 0; ni < 3; ++ni) {
                int col = col0 + wc + ni * 16 + lr;
                float v = acc[mi][ni][rr];
                if (col < 512)      xsb[(size_t)row * HC + col] = (short)f2bf(v);
                else if (col < 520) a_srcv[(size_t)row * 8 + (col - 512)] = v;
                else if (col < 528) a_dstv[(size_t)row * 8 + (col - 520)] = v;
            }
        }
    }
}

// ---------------------------------------------------------------------------
__global__ void deg_count(const int* __restrict__ ei, int* __restrict__ deg) {
    int e = blockIdx.x * blockDim.x + threadIdx.x;
    if (e < N_EDGES) atomicAdd(&deg[ei[N_EDGES + e]], 1);
}

// 1 block, 256 threads; each thread scans 80 contiguous elements.
__global__ void scan_kernel(const int* __restrict__ deg,
                            int* __restrict__ off,
                            int* __restrict__ cursor) {
    __shared__ int wtot[4];
    int t = threadIdx.x;
    int lane = t & 63, w = t >> 6;
    int base = t * 80;
    int s = 0;
    for (int i = 0; i < 80; ++i) {
        int idx = base + i;
        if (idx < N_NODES) s += deg[idx];
    }
    int v = s;
    #pragma unroll
    for (int o = 1; o < 64; o <<= 1) {
        int u = __shfl_up(v, o);
        if (lane >= o) v += u;
    }
    if (lane == 63) wtot[w] = v;
    __syncthreads();
    int add = 0;
    for (int j = 0; j < w; ++j) add += wtot[j];
    int run = add + v - s;
    for (int i = 0; i < 80; ++i) {
        int idx = base + i;
        if (idx < N_NODES) {
            off[idx] = run; cursor[idx] = run;
            run += deg[idx];
        }
    }
    if (t == 255) off[N_NODES] = run;
}

// ---------------------------------------------------------------------------
// bare CSR scatter: csr_src[idx] = src, sorted by dst.  Scores are recomputed
// on the fly in aggregate_ln (saves the 20.5 MB csr_ex round-trip).
__global__ void edge_scatter(const int* __restrict__ ei,
                             int* __restrict__ cursor,
                             int* __restrict__ csr_src) {
    int e = blockIdx.x * blockDim.x + threadIdx.x;
    if (e >= N_EDGES) return;
    int d = ei[N_EDGES + e];
    int idx = atomicAdd(&cursor[d], 1);
    csr_src[idx] = ei[e];
}

// ---------------------------------------------------------------------------
// one block per destination node: on-the-fly softmax weights + weighted
// aggregation of incoming bf16 xs rows, then fused bias + LayerNorm + PReLU.
// Softmax max-shift skipped: shift-invariant, scores O(+-5).
__global__ __launch_bounds__(256) void aggregate_ln(
        const int* __restrict__ off,
        const int* __restrict__ csr_src,
        const float* __restrict__ a_srcv,
        const float* __restrict__ a_dstv,
        const short* __restrict__ xsb,
        const float* __restrict__ bias,
        const float* __restrict__ gamma,
        const float* __restrict__ beta,
        const float* __restrict__ prelu_a,
        float* __restrict__ out) {
    int n  = blockIdx.x;
    int t  = threadIdx.x;
    int ch = t * 2;
    int h  = ch >> 6;
    int start = off[n], end = off[n + 1];

    float ad = a_dstv[(size_t)n * 8 + h];   // hoisted per-node dst score

    float ax = 0.f, ay = 0.f, wsum = 0.f;
    int i = start;
    for (; i + 1 < end; i += 2) {
        int s0 = csr_src[i];
        int s1 = csr_src[i + 1];
        float sc0 = a_srcv[(size_t)s0 * 8 + h] + ad;
        float sc1 = a_srcv[(size_t)s1 * 8 + h] + ad;
        sc0 = (sc0 >= 0.f) ? sc0 : LEAKY * sc0;
        sc1 = (sc1 >= 0.f) ? sc1 : LEAKY * sc1;
        float w0 = __expf(sc0);
        float w1 = __expf(sc1);
        unsigned int v0 = *(const unsigned int*)(xsb + (size_t)s0 * HC + ch);
        unsigned int v1 = *(const unsigned int*)(xsb + (size_t)s1 * HC + ch);
        ax = fmaf(w0, bf2f(v0 & 0xffffu), ax);
        ay = fmaf(w0, bf2f(v0 >> 16), ay);
        ax = fmaf(w1, bf2f(v1 & 0xffffu), ax);
        ay = fmaf(w1, bf2f(v1 >> 16), ay);
        wsum += w0 + w1;
    }
    if (i < end) {
        int s0 = csr_src[i];
        float sc0 = a_srcv[(size_t)s0 * 8 + h] + ad;
        sc0 = (sc0 >= 0.f) ? sc0 : LEAKY * sc0;
        float w0 = __expf(sc0);
        unsigned int v0 = *(const unsigned int*)(xsb + (size_t)s0 * HC + ch);
        ax = fmaf(w0, bf2f(v0 & 0xffffu), ax);
        ay = fmaf(w0, bf2f(v0 >> 16), ay);
        wsum += w0;
    }
    float inv = 1.f / (wsum + 1e-16f);
    float vx = ax * inv + bias[ch];
    float vy = ay * inv + bias[ch + 1];

    float sum = vx + vy;
    float sq  = vx * vx + vy * vy;
    #pragma unroll
    for (int o = 32; o > 0; o >>= 1) {
        sum += __shfl_down(sum, o);
        sq  += __shfl_down(sq, o);
    }
    __shared__ float s_sum[4], s_sq[4];
    int wid = t >> 6;
    if ((t & 63) == 0) { s_sum[wid] = sum; s_sq[wid] = sq; }
    __syncthreads();
    float ts = s_sum[0] + s_sum[1] + s_sum[2] + s_sum[3];
    float tq = s_sq[0] + s_sq[1] + s_sq[2] + s_sq[3];
    float mu   = ts * (1.f / (float)HC);
    float var  = tq * (1.f / (float)HC) - mu * mu;
    float rstd = rsqrtf(var + LN_EPS);

    float y0 = (vx - mu) * rstd * gamma[ch]     + beta[ch];
    float y1 = (vy - mu) * rstd * gamma[ch + 1] + beta[ch + 1];
    y0 = (y0 >= 0.f) ? y0 : prelu_a[ch] * y0;
    y1 = (y1 >= 0.f) ? y1 : prelu_a[ch + 1] * y1;
    *(float2*)(out + (size_t)n * HC + ch) = make_float2(y0, y1);
}

// ---------------------------------------------------------------------------
extern "C" void kernel_launch(void* const* d_in, const int* in_sizes, int n_in,
                              void* d_out, int out_size, void* d_ws, size_t ws_size,
                              hipStream_t stream) {
    const float* x        = (const float*)d_in[0];
    const int*   ei       = (const int*)d_in[2];
    const float* Wsrc     = (const float*)d_in[4];
    const float* Wdst     = (const float*)d_in[5];
    const float* att_src  = (const float*)d_in[6];
    const float* att_dst  = (const float*)d_in[7];
    const float* bias     = (const float*)d_in[8];
    const float* gamma    = (const float*)d_in[9];
    const float* beta     = (const float*)d_in[10];
    const float* prelu_a  = (const float*)d_in[11];
    float* out            = (float*)d_out;

    char*  ws = (char*)d_ws;
    size_t o  = 0;
    auto alloc = [&](size_t bytes) -> void* {
        void* p = ws + o;
        o += (bytes + 255) & ~(size_t)255;
        return p;
    };
    short* wbT     = (short*)alloc(sizeof(short) * BCOLS * IN_DIM);        // 1.18 MB
    short* xsb     = (short*)alloc(sizeof(short) * (size_t)N_NODES * HC);  // 20.5 MB
    float* a_srcv  = (float*)alloc(sizeof(float) * N_NODES * 8);
    float* a_dstv  = (float*)alloc(sizeof(float) * N_NODES * 8);
    int*   deg     = (int*)alloc(sizeof(int) * N_NODES);
    int*   off     = (int*)alloc(sizeof(int) * (N_NODES + 1));
    int*   cursor  = (int*)alloc(sizeof(int) * N_NODES);
    int*   csr_src = (int*)alloc(sizeof(int) * N_EDGES);                   // 1.28 MB

    // xb (bf16 x) lives in d_out: exactly N*1024*2B = N*512*4B; d_out is dead
    // until aggregate_ln fully overwrites it.
    short* xb = (short*)d_out;

    hipMemsetAsync(deg, 0, sizeof(int) * N_NODES, stream);

    convert_x<<<2048, 256, 0, stream>>>(x, xb);
    prep_w<<<IN_DIM, 128, 0, stream>>>(Wsrc, Wdst, att_src, att_dst, wbT);

    gemm_mfma<<<NWG, 256, 0, stream>>>(xb, wbT, xsb, a_srcv, a_dstv);

    deg_count<<<(N_EDGES + 255) / 256, 256, 0, stream>>>(ei, deg);
    scan_kernel<<<1, 256, 0, stream>>>(deg, off, cursor);
    edge_scatter<<<(N_EDGES + 255) / 256, 256, 0, stream>>>(ei, cursor, csr_src);
    aggregate_ln<<<N_NODES, 256, 0, stream>>>(
        off, csr_src, a_srcv, a_dstv, xsb, bias, gamma, beta, prelu_a, out);
}